// Round 8
// baseline (1121.897 us; speedup 1.0000x reference)
//
#include <hip/hip_runtime.h>
#include <math.h>

#define N_TEAMS 100000
#define N_EDGES 1600000
#define BATCH   16384
#define DIM     64
#define SLOPE   0.01f
#define NPAD    100352  // 98 * 1024

__device__ __forceinline__ float leaky(float v) { return v > 0.f ? v : SLOPE * v; }

__device__ __forceinline__ float bf2f(unsigned short u) {
    return __uint_as_float(((unsigned)u) << 16);
}
__device__ __forceinline__ unsigned short f2bf(float f) {
    unsigned b = __float_as_uint(f);
    unsigned r = b + 0x7FFFu + ((b >> 16) & 1u);  // RNE
    return (unsigned short)(r >> 16);
}

// ---- setup ---------------------------------------------------------------

__global__ void k_zero(int* __restrict__ cnt, int n) {
    int i = blockIdx.x * blockDim.x + threadIdx.x;
    if (i < n) cnt[i] = 0;
}

__global__ void k_cnt(const int* __restrict__ dst, int* __restrict__ cnt, int E) {
    int e = blockIdx.x * blockDim.x + threadIdx.x;
    if (e < E) atomicAdd(&cnt[__builtin_nontemporal_load(dst + e)], 1);
}

// ---- 2-level exclusive scan of cnt -> row_start (+ fill copy) ------------

__global__ __launch_bounds__(1024) void k_scan1(const int* __restrict__ cnt,
                                                int* __restrict__ excl,
                                                int* __restrict__ partial, int n) {
    __shared__ int s[1024];
    int tid = threadIdx.x;
    int i = blockIdx.x * 1024 + tid;
    int v = (i < n) ? cnt[i] : 0;
    s[tid] = v;
    __syncthreads();
    for (int off = 1; off < 1024; off <<= 1) {
        int t = (tid >= off) ? s[tid - off] : 0;
        __syncthreads();
        s[tid] += t;
        __syncthreads();
    }
    excl[i] = s[tid] - v;
    if (tid == 1023) partial[blockIdx.x] = s[1023];
}

__global__ __launch_bounds__(128) void k_scan2(int* __restrict__ partial, int nb) {
    __shared__ int s[128];
    int tid = threadIdx.x;
    int v = (tid < nb) ? partial[tid] : 0;
    s[tid] = v;
    __syncthreads();
    for (int off = 1; off < 128; off <<= 1) {
        int t = (tid >= off) ? s[tid - off] : 0;
        __syncthreads();
        s[tid] += t;
        __syncthreads();
    }
    if (tid < nb) partial[tid] = s[tid] - v;  // exclusive
}

__global__ __launch_bounds__(1024) void k_scan3(int* __restrict__ row_start,
                                                int* __restrict__ fill,
                                                const int* __restrict__ partial) {
    int i = blockIdx.x * 1024 + threadIdx.x;
    int v = row_start[i] + partial[blockIdx.x];
    row_start[i] = v;
    fill[i] = v;
}

// ---- bucket edges into CSR slots: packed (src, raw weight) ---------------

__global__ void k_bucket(const int* __restrict__ src, const int* __restrict__ dst,
                         const float* __restrict__ w, int* __restrict__ fill,
                         int2* __restrict__ edges, int E) {
    int e = blockIdx.x * blockDim.x + threadIdx.x;
    if (e < E) {
        int s = __builtin_nontemporal_load(src + e);
        int d = __builtin_nontemporal_load(dst + e);
        float wv = __builtin_nontemporal_load(w + e);
        int p = atomicAdd(&fill[d], 1);
        edges[p] = make_int2(s, __float_as_int(wv));
    }
}

// ---- dinv: thread per row, sum raw weights over own CSR range ------------

__global__ void k_dinv(const int* __restrict__ row_start,
                       const int* __restrict__ edges_i,  // int view of edges
                       float* __restrict__ dinv, int n) {
    int r = blockIdx.x * blockDim.x + threadIdx.x;
    if (r >= n) return;
    int beg = row_start[r], end = row_start[r + 1];
    float s = 1.0f;  // self-loop
    for (int j = beg; j < end; j++) s += __int_as_float(edges_i[2 * j + 1]);
    dinv[r] = rsqrtf(fmaxf(s, 1e-12f));
}

// ---- emb -> pre-scaled bf16 table: xb[row][d] = dinv[row]*emb[row][d] ----

__global__ void k_cvt(const float* __restrict__ emb, const float* __restrict__ dinv,
                      unsigned short* __restrict__ xb, int n4) {
    int i = blockIdx.x * blockDim.x + threadIdx.x;
    if (i >= n4) return;
    int row = i >> 4;  // 16 float4 per row
    float di = dinv[row];
    float4 v = ((const float4*)emb)[i];
    ushort4 o;
    o.x = f2bf(di * v.x); o.y = f2bf(di * v.y);
    o.z = f2bf(di * v.z); o.w = f2bf(di * v.w);
    ((ushort4*)xb)[i] = o;
}

// ---- fused layer: y = leaky((A @ x) @ W + b) -----------------------------
// Persistent (2048 blocks = 8/CU, 16KB LDS each, VGPR capped for 32 waves/CU).
// One row per wave, 8-deep gather pipeline (R4 structure), W staged once.
// Table pre-scaled by dinv; epilogue multiplies by dinv_row; optional
// output pre-scale for the next layer.

__global__ __launch_bounds__(256, 8) void k_layer(
    const unsigned short* __restrict__ xb, const int* __restrict__ row_start,
    const long long* __restrict__ edges, const float* __restrict__ dinv,
    const float* __restrict__ W, const float* __restrict__ b,
    unsigned short* __restrict__ yb, int n, int nwaves, int scale_out) {
    __shared__ float Ws[64 * 64];
    int tid = threadIdx.x;
    const float4* Wv = (const float4*)W;
    float4* Wsv = (float4*)Ws;
#pragma unroll
    for (int i = 0; i < 4; i++) Wsv[tid + i * 256] = Wv[tid + i * 256];
    __syncthreads();
    int lane = tid & 63;
    int wv0 = blockIdx.x * 4 + (tid >> 6);
    float bl = b[lane];
    for (int row = wv0; row < n; row += nwaves) {
        int beg = row_start[row];
        int c = row_start[row + 1] - beg;
        float di = dinv[row];
        float acc = bf2f(xb[((unsigned)row << 6) + lane]);  // self (pre-scaled)
        const long long* ep = edges + beg;
        int j = 0;
        int chunks = c >> 3;
        if (chunks > 0) {
            long long ev[8];
#pragma unroll
            for (int k = 0; k < 8; k++) ev[k] = __builtin_nontemporal_load(ep + k);
            for (int t = 1; t <= chunks; t++) {
                float nv[8], xv[8];
#pragma unroll
                for (int k = 0; k < 8; k++) {
                    int s = (int)ev[k];
                    nv[k] = __int_as_float((int)(ev[k] >> 32));
                    xv[k] = bf2f(xb[((unsigned)s << 6) + lane]);  // 8 in-flight gathers
                }
                if (t < chunks) {
                    const long long* np = ep + (size_t)t * 8;
#pragma unroll
                    for (int k = 0; k < 8; k++) ev[k] = __builtin_nontemporal_load(np + k);
                }
#pragma unroll
                for (int k = 0; k < 8; k++) acc = fmaf(nv[k], xv[k], acc);
            }
            j = chunks * 8;
        }
        if (j + 4 <= c) {
            long long e0 = __builtin_nontemporal_load(ep + j + 0);
            long long e1 = __builtin_nontemporal_load(ep + j + 1);
            long long e2 = __builtin_nontemporal_load(ep + j + 2);
            long long e3 = __builtin_nontemporal_load(ep + j + 3);
            float x0 = bf2f(xb[((unsigned)(int)e0 << 6) + lane]);
            float x1 = bf2f(xb[((unsigned)(int)e1 << 6) + lane]);
            float x2 = bf2f(xb[((unsigned)(int)e2 << 6) + lane]);
            float x3 = bf2f(xb[((unsigned)(int)e3 << 6) + lane]);
            acc = fmaf(__int_as_float((int)(e0 >> 32)), x0, acc);
            acc = fmaf(__int_as_float((int)(e1 >> 32)), x1, acc);
            acc = fmaf(__int_as_float((int)(e2 >> 32)), x2, acc);
            acc = fmaf(__int_as_float((int)(e3 >> 32)), x3, acc);
            j += 4;
        }
        for (; j < c; j++) {
            long long e0 = __builtin_nontemporal_load(ep + j);
            acc = fmaf(__int_as_float((int)(e0 >> 32)),
                       bf2f(xb[((unsigned)(int)e0 << 6) + lane]), acc);
        }
        acc *= di;
        // in-wave GEMM: o[lane] = sum_k acc[k] * W[k][lane]
        float o = bl;
#pragma unroll
        for (int k = 0; k < 64; k++) {
            float xk = __shfl(acc, k, 64);
            o = fmaf(xk, Ws[k * 64 + lane], o);
        }
        o = leaky(o);
        if (scale_out) o *= di;
        yb[((unsigned)row << 6) + lane] = f2bf(o);
    }
}

// ---- head MLP (bf16 activations in, row-major) ---------------------------

__global__ __launch_bounds__(256) void k_head(
    const unsigned short* __restrict__ xb, const int* __restrict__ home,
    const int* __restrict__ away, const float* __restrict__ W1,
    const float* __restrict__ b1, const float* __restrict__ W3,
    const float* __restrict__ b3, float* __restrict__ z2, int B) {
    __shared__ float W1s[128 * 6];
    __shared__ float b1s[6], W3s[18], b3s[3];
    int tid = threadIdx.x;
    for (int i = tid; i < 768; i += 256) W1s[i] = W1[i];
    if (tid < 6) b1s[tid] = b1[tid];
    if (tid < 18) W3s[tid] = W3[tid];
    if (tid < 3) b3s[tid] = b3[tid];
    __syncthreads();
    int i = blockIdx.x * 256 + tid;
    if (i >= B) return;
    float z1[6];
#pragma unroll
    for (int j = 0; j < 6; j++) z1[j] = b1s[j];
    const uint4* rows[2];
    rows[0] = (const uint4*)(xb + (size_t)home[i] * 64);
    rows[1] = (const uint4*)(xb + (size_t)away[i] * 64);
#pragma unroll
    for (int h = 0; h < 2; h++) {
        const uint4* r = rows[h];
        int base = h * 64;
#pragma unroll
        for (int k = 0; k < 8; k++) {   // 8 x uint4 = 64 bf16 dims
            uint4 v = r[k];
            unsigned uu[4] = {v.x, v.y, v.z, v.w};
#pragma unroll
            for (int t = 0; t < 4; t++) {
                float fx = bf2f((unsigned short)(uu[t] & 0xFFFF));
                float fy = bf2f((unsigned short)(uu[t] >> 16));
                int d = base + k * 8 + t * 2;
#pragma unroll
                for (int j = 0; j < 6; j++) {
                    z1[j] = fmaf(fx, W1s[d * 6 + j], z1[j]);
                    z1[j] = fmaf(fy, W1s[(d + 1) * 6 + j], z1[j]);
                }
            }
        }
    }
#pragma unroll
    for (int j = 0; j < 6; j++) z1[j] = leaky(z1[j]);
#pragma unroll
    for (int c = 0; c < 3; c++) {
        float s = b3s[c];
#pragma unroll
        for (int j = 0; j < 6; j++) s = fmaf(z1[j], W3s[j * 3 + c], s);
        z2[(size_t)i * 3 + c] = leaky(s);
    }
}

// ---- column-wise log-softmax ---------------------------------------------

__global__ __launch_bounds__(1024) void k_stats(const float* __restrict__ z2,
                                                float* __restrict__ stats, int B) {
    __shared__ float red[3][1024];
    int tid = threadIdx.x;
    float m[3] = {-1e30f, -1e30f, -1e30f};
    for (int i = tid; i < B; i += 1024) {
        m[0] = fmaxf(m[0], z2[3 * i + 0]);
        m[1] = fmaxf(m[1], z2[3 * i + 1]);
        m[2] = fmaxf(m[2], z2[3 * i + 2]);
    }
    for (int c = 0; c < 3; c++) red[c][tid] = m[c];
    __syncthreads();
    for (int s = 512; s > 0; s >>= 1) {
        if (tid < s)
            for (int c = 0; c < 3; c++) red[c][tid] = fmaxf(red[c][tid], red[c][tid + s]);
        __syncthreads();
    }
    float M[3];
    for (int c = 0; c < 3; c++) M[c] = red[c][0];
    __syncthreads();
    float sum[3] = {0.f, 0.f, 0.f};
    for (int i = tid; i < B; i += 1024) {
        sum[0] += expf(z2[3 * i + 0] - M[0]);
        sum[1] += expf(z2[3 * i + 1] - M[1]);
        sum[2] += expf(z2[3 * i + 2] - M[2]);
    }
    for (int c = 0; c < 3; c++) red[c][tid] = sum[c];
    __syncthreads();
    for (int s = 512; s > 0; s >>= 1) {
        if (tid < s)
            for (int c = 0; c < 3; c++) red[c][tid] += red[c][tid + s];
        __syncthreads();
    }
    if (tid == 0)
        for (int c = 0; c < 3; c++) { stats[c] = M[c]; stats[3 + c] = logf(red[c][0]); }
}

__global__ void k_final(const float* __restrict__ z2, const float* __restrict__ stats,
                        float* __restrict__ out, int n) {
    int i = blockIdx.x * blockDim.x + threadIdx.x;
    if (i < n) {
        int c = i % 3;
        out[i] = z2[i] - stats[c] - stats[3 + c];
    }
}

// ---- launch --------------------------------------------------------------

extern "C" void kernel_launch(void* const* d_in, const int* in_sizes, int n_in,
                              void* d_out, int out_size, void* d_ws, size_t ws_size,
                              hipStream_t stream) {
    const int*   edge_index = (const int*)d_in[0];
    const int*   src  = edge_index;
    const int*   dst  = edge_index + N_EDGES;
    const float* ew   = (const float*)d_in[1];
    const int*   home = (const int*)d_in[2];
    const int*   away = (const int*)d_in[3];
    const float* emb  = (const float*)d_in[4];
    const float* W0 = (const float*)d_in[5];  const float* b0 = (const float*)d_in[6];
    const float* W1 = (const float*)d_in[7];  const float* b1 = (const float*)d_in[8];
    const float* W2 = (const float*)d_in[9];  const float* b2 = (const float*)d_in[10];
    const float* l1W = (const float*)d_in[11]; const float* l1b = (const float*)d_in[12];
    const float* l3W = (const float*)d_in[13]; const float* l3b = (const float*)d_in[14];

    char* p = (char*)d_ws;
    float*          dinv      = (float*)p;          p += NPAD * 4;
    int*            cnt       = (int*)p;            p += NPAD * 4;
    int*            fill      = (int*)p;            p += NPAD * 4;
    int*            row_start = (int*)p;            p += (NPAD + 1024) * 4;
    int*            partial   = (int*)p;            p += 128 * 4;
    int2*           edges     = (int2*)p;           p += (size_t)N_EDGES * 8;
    unsigned short* xbA       = (unsigned short*)p; p += (size_t)N_TEAMS * 64 * 2;
    unsigned short* xbB       = (unsigned short*)p; p += (size_t)N_TEAMS * 64 * 2;
    float*          z2        = (float*)p;          p += (size_t)BATCH * 3 * 4;
    float*          stats     = (float*)p;

    const int scanBlocks = NPAD / 1024;  // 98

    // ---- CSR build (once, reused by all 3 layers) ----
    k_zero<<<NPAD / 256, 256, 0, stream>>>(cnt, NPAD);
    k_cnt<<<(N_EDGES + 255) / 256, 256, 0, stream>>>(dst, cnt, N_EDGES);
    k_scan1<<<scanBlocks, 1024, 0, stream>>>(cnt, row_start, partial, N_TEAMS);
    k_scan2<<<1, 128, 0, stream>>>(partial, scanBlocks);
    k_scan3<<<scanBlocks, 1024, 0, stream>>>(row_start, fill, partial);
    k_bucket<<<(N_EDGES + 255) / 256, 256, 0, stream>>>(src, dst, ew, fill, edges, N_EDGES);
    k_dinv<<<(N_TEAMS + 255) / 256, 256, 0, stream>>>(row_start, (const int*)edges, dinv, N_TEAMS);
    k_cvt<<<(N_TEAMS * 16 + 255) / 256, 256, 0, stream>>>(emb, dinv, xbA, N_TEAMS * 16);

    const int LBLOCKS = 2048;            // persistent: exactly 8 blocks/CU
    const int LWAVES  = LBLOCKS * 4;     // 8192 waves, ~12 rows each

    // layer 0..2 fused: agg + GEMM + bias + leaky (+ dinv pre-scale for next)
    k_layer<<<LBLOCKS, 256, 0, stream>>>(xbA, row_start, (const long long*)edges, dinv,
                                         W0, b0, xbB, N_TEAMS, LWAVES, 1);
    k_layer<<<LBLOCKS, 256, 0, stream>>>(xbB, row_start, (const long long*)edges, dinv,
                                         W1, b1, xbA, N_TEAMS, LWAVES, 1);
    k_layer<<<LBLOCKS, 256, 0, stream>>>(xbA, row_start, (const long long*)edges, dinv,
                                         W2, b2, xbB, N_TEAMS, LWAVES, 0);

    // head + column log-softmax
    k_head<<<(BATCH + 255) / 256, 256, 0, stream>>>(xbB, home, away, l1W, l1b, l3W, l3b, z2, BATCH);
    k_stats<<<1, 1024, 0, stream>>>(z2, stats, BATCH);
    k_final<<<(BATCH * 3 + 255) / 256, 256, 0, stream>>>(z2, stats, (float*)d_out, BATCH * 3);
}

// Round 9
// 680.798 us; speedup vs baseline: 1.6479x; 1.6479x over previous
//
#include <hip/hip_runtime.h>
#include <math.h>

#define N_TEAMS 100000
#define N_EDGES 1600000
#define BATCH   16384
#define DIM     64
#define SLOPE   0.01f
#define NPAD    100352  // 98 * 1024

__device__ __forceinline__ float leaky(float v) { return v > 0.f ? v : SLOPE * v; }

__device__ __forceinline__ float bf2f(unsigned short u) {
    return __uint_as_float(((unsigned)u) << 16);
}
__device__ __forceinline__ unsigned short f2bf(float f) {
    unsigned b = __float_as_uint(f);
    unsigned r = b + 0x7FFFu + ((b >> 16) & 1u);  // RNE
    return (unsigned short)(r >> 16);
}

// ---- setup ---------------------------------------------------------------

__global__ void k_zero(int* __restrict__ cnt, int n) {
    int i = blockIdx.x * blockDim.x + threadIdx.x;
    if (i < n) cnt[i] = 0;
}

__global__ void k_cnt(const int* __restrict__ dst, int* __restrict__ cnt, int E) {
    int e = blockIdx.x * blockDim.x + threadIdx.x;
    if (e < E) atomicAdd(&cnt[__builtin_nontemporal_load(dst + e)], 1);
}

// ---- 2-level exclusive scan of cnt -> row_start (+ fill copy) ------------

__global__ __launch_bounds__(1024) void k_scan1(const int* __restrict__ cnt,
                                                int* __restrict__ excl,
                                                int* __restrict__ partial, int n) {
    __shared__ int s[1024];
    int tid = threadIdx.x;
    int i = blockIdx.x * 1024 + tid;
    int v = (i < n) ? cnt[i] : 0;
    s[tid] = v;
    __syncthreads();
    for (int off = 1; off < 1024; off <<= 1) {
        int t = (tid >= off) ? s[tid - off] : 0;
        __syncthreads();
        s[tid] += t;
        __syncthreads();
    }
    excl[i] = s[tid] - v;
    if (tid == 1023) partial[blockIdx.x] = s[1023];
}

__global__ __launch_bounds__(128) void k_scan2(int* __restrict__ partial, int nb) {
    __shared__ int s[128];
    int tid = threadIdx.x;
    int v = (tid < nb) ? partial[tid] : 0;
    s[tid] = v;
    __syncthreads();
    for (int off = 1; off < 128; off <<= 1) {
        int t = (tid >= off) ? s[tid - off] : 0;
        __syncthreads();
        s[tid] += t;
        __syncthreads();
    }
    if (tid < nb) partial[tid] = s[tid] - v;  // exclusive
}

__global__ __launch_bounds__(1024) void k_scan3(int* __restrict__ row_start,
                                                int* __restrict__ fill,
                                                const int* __restrict__ partial) {
    int i = blockIdx.x * 1024 + threadIdx.x;
    int v = row_start[i] + partial[blockIdx.x];
    row_start[i] = v;
    fill[i] = v;
}

// ---- bucket edges into CSR slots: packed (src, raw weight) ---------------

__global__ void k_bucket(const int* __restrict__ src, const int* __restrict__ dst,
                         const float* __restrict__ w, int* __restrict__ fill,
                         int2* __restrict__ edges, int E) {
    int e = blockIdx.x * blockDim.x + threadIdx.x;
    if (e < E) {
        int s = __builtin_nontemporal_load(src + e);
        int d = __builtin_nontemporal_load(dst + e);
        float wv = __builtin_nontemporal_load(w + e);
        int p = atomicAdd(&fill[d], 1);
        edges[p] = make_int2(s, __float_as_int(wv));
    }
}

// ---- dinv: thread per row, sum raw weights over own CSR range ------------

__global__ void k_dinv(const int* __restrict__ row_start,
                       const int* __restrict__ edges_i,  // int view of edges
                       float* __restrict__ dinv, int n) {
    int r = blockIdx.x * blockDim.x + threadIdx.x;
    if (r >= n) return;
    int beg = row_start[r], end = row_start[r + 1];
    float s = 1.0f;  // self-loop
    for (int j = beg; j < end; j++) s += __int_as_float(edges_i[2 * j + 1]);
    dinv[r] = rsqrtf(fmaxf(s, 1e-12f));
}

// ---- emb -> pre-scaled bf16 table: xb[row][d] = dinv[row]*emb[row][d] ----

__global__ void k_cvt(const float* __restrict__ emb, const float* __restrict__ dinv,
                      unsigned short* __restrict__ xb, int n4) {
    int i = blockIdx.x * blockDim.x + threadIdx.x;
    if (i >= n4) return;
    int row = i >> 4;  // 16 float4 per row
    float di = dinv[row];
    float4 v = ((const float4*)emb)[i];
    ushort4 o;
    o.x = f2bf(di * v.x); o.y = f2bf(di * v.y);
    o.z = f2bf(di * v.z); o.w = f2bf(di * v.w);
    ((ushort4*)xb)[i] = o;
}

// ---- fused layer: y = leaky((A @ x) @ W + b) -----------------------------
// Persistent 2048 blocks (8/CU by LDS), one row per wave, 8-deep gather
// pipeline (R4's proven codegen: NO min-waves bound -> no spills),
// W staged once per block. Table pre-scaled by dinv.

__global__ __launch_bounds__(256) void k_layer(
    const unsigned short* __restrict__ xb, const int* __restrict__ row_start,
    const long long* __restrict__ edges, const float* __restrict__ dinv,
    const float* __restrict__ W, const float* __restrict__ b,
    unsigned short* __restrict__ yb, int n, int nwaves, int scale_out) {
    __shared__ float Ws[64 * 64];
    int tid = threadIdx.x;
    const float4* Wv = (const float4*)W;
    float4* Wsv = (float4*)Ws;
#pragma unroll
    for (int i = 0; i < 4; i++) Wsv[tid + i * 256] = Wv[tid + i * 256];
    __syncthreads();
    int lane = tid & 63;
    int wv0 = blockIdx.x * 4 + (tid >> 6);
    float bl = b[lane];
    for (int row = wv0; row < n; row += nwaves) {
        int beg = row_start[row];
        int c = row_start[row + 1] - beg;
        float di = dinv[row];
        float acc = bf2f(xb[((unsigned)row << 6) + lane]);  // self (pre-scaled)
        const long long* ep = edges + beg;
        int j = 0;
        int chunks = c >> 3;
        if (chunks > 0) {
            long long ev[8];
#pragma unroll
            for (int k = 0; k < 8; k++) ev[k] = __builtin_nontemporal_load(ep + k);
            for (int t = 1; t <= chunks; t++) {
                float nv[8], xv[8];
#pragma unroll
                for (int k = 0; k < 8; k++) {
                    int s = (int)ev[k];
                    nv[k] = __int_as_float((int)(ev[k] >> 32));
                    xv[k] = bf2f(xb[((unsigned)s << 6) + lane]);  // 8 in-flight gathers
                }
                if (t < chunks) {
                    const long long* np = ep + (size_t)t * 8;
#pragma unroll
                    for (int k = 0; k < 8; k++) ev[k] = __builtin_nontemporal_load(np + k);
                }
#pragma unroll
                for (int k = 0; k < 8; k++) acc = fmaf(nv[k], xv[k], acc);
            }
            j = chunks * 8;
        }
        if (j + 4 <= c) {
            long long e0 = __builtin_nontemporal_load(ep + j + 0);
            long long e1 = __builtin_nontemporal_load(ep + j + 1);
            long long e2 = __builtin_nontemporal_load(ep + j + 2);
            long long e3 = __builtin_nontemporal_load(ep + j + 3);
            float x0 = bf2f(xb[((unsigned)(int)e0 << 6) + lane]);
            float x1 = bf2f(xb[((unsigned)(int)e1 << 6) + lane]);
            float x2 = bf2f(xb[((unsigned)(int)e2 << 6) + lane]);
            float x3 = bf2f(xb[((unsigned)(int)e3 << 6) + lane]);
            acc = fmaf(__int_as_float((int)(e0 >> 32)), x0, acc);
            acc = fmaf(__int_as_float((int)(e1 >> 32)), x1, acc);
            acc = fmaf(__int_as_float((int)(e2 >> 32)), x2, acc);
            acc = fmaf(__int_as_float((int)(e3 >> 32)), x3, acc);
            j += 4;
        }
        for (; j < c; j++) {
            long long e0 = __builtin_nontemporal_load(ep + j);
            acc = fmaf(__int_as_float((int)(e0 >> 32)),
                       bf2f(xb[((unsigned)(int)e0 << 6) + lane]), acc);
        }
        acc *= di;
        // in-wave GEMM: o[lane] = sum_k acc[k] * W[k][lane]
        float o = bl;
#pragma unroll
        for (int k = 0; k < 64; k++) {
            float xk = __shfl(acc, k, 64);
            o = fmaf(xk, Ws[k * 64 + lane], o);
        }
        o = leaky(o);
        if (scale_out) o *= di;
        yb[((unsigned)row << 6) + lane] = f2bf(o);
    }
}

// ---- head MLP (bf16 activations in, row-major) ---------------------------

__global__ __launch_bounds__(256) void k_head(
    const unsigned short* __restrict__ xb, const int* __restrict__ home,
    const int* __restrict__ away, const float* __restrict__ W1,
    const float* __restrict__ b1, const float* __restrict__ W3,
    const float* __restrict__ b3, float* __restrict__ z2, int B) {
    __shared__ float W1s[128 * 6];
    __shared__ float b1s[6], W3s[18], b3s[3];
    int tid = threadIdx.x;
    for (int i = tid; i < 768; i += 256) W1s[i] = W1[i];
    if (tid < 6) b1s[tid] = b1[tid];
    if (tid < 18) W3s[tid] = W3[tid];
    if (tid < 3) b3s[tid] = b3[tid];
    __syncthreads();
    int i = blockIdx.x * 256 + tid;
    if (i >= B) return;
    float z1[6];
#pragma unroll
    for (int j = 0; j < 6; j++) z1[j] = b1s[j];
    const uint4* rows[2];
    rows[0] = (const uint4*)(xb + (size_t)home[i] * 64);
    rows[1] = (const uint4*)(xb + (size_t)away[i] * 64);
#pragma unroll
    for (int h = 0; h < 2; h++) {
        const uint4* r = rows[h];
        int base = h * 64;
#pragma unroll
        for (int k = 0; k < 8; k++) {   // 8 x uint4 = 64 bf16 dims
            uint4 v = r[k];
            unsigned uu[4] = {v.x, v.y, v.z, v.w};
#pragma unroll
            for (int t = 0; t < 4; t++) {
                float fx = bf2f((unsigned short)(uu[t] & 0xFFFF));
                float fy = bf2f((unsigned short)(uu[t] >> 16));
                int d = base + k * 8 + t * 2;
#pragma unroll
                for (int j = 0; j < 6; j++) {
                    z1[j] = fmaf(fx, W1s[d * 6 + j], z1[j]);
                    z1[j] = fmaf(fy, W1s[(d + 1) * 6 + j], z1[j]);
                }
            }
        }
    }
#pragma unroll
    for (int j = 0; j < 6; j++) z1[j] = leaky(z1[j]);
#pragma unroll
    for (int c = 0; c < 3; c++) {
        float s = b3s[c];
#pragma unroll
        for (int j = 0; j < 6; j++) s = fmaf(z1[j], W3s[j * 3 + c], s);
        z2[(size_t)i * 3 + c] = leaky(s);
    }
}

// ---- column-wise log-softmax ---------------------------------------------

__global__ __launch_bounds__(1024) void k_stats(const float* __restrict__ z2,
                                                float* __restrict__ stats, int B) {
    __shared__ float red[3][1024];
    int tid = threadIdx.x;
    float m[3] = {-1e30f, -1e30f, -1e30f};
    for (int i = tid; i < B; i += 1024) {
        m[0] = fmaxf(m[0], z2[3 * i + 0]);
        m[1] = fmaxf(m[1], z2[3 * i + 1]);
        m[2] = fmaxf(m[2], z2[3 * i + 2]);
    }
    for (int c = 0; c < 3; c++) red[c][tid] = m[c];
    __syncthreads();
    for (int s = 512; s > 0; s >>= 1) {
        if (tid < s)
            for (int c = 0; c < 3; c++) red[c][tid] = fmaxf(red[c][tid], red[c][tid + s]);
        __syncthreads();
    }
    float M[3];
    for (int c = 0; c < 3; c++) M[c] = red[c][0];
    __syncthreads();
    float sum[3] = {0.f, 0.f, 0.f};
    for (int i = tid; i < B; i += 1024) {
        sum[0] += expf(z2[3 * i + 0] - M[0]);
        sum[1] += expf(z2[3 * i + 1] - M[1]);
        sum[2] += expf(z2[3 * i + 2] - M[2]);
    }
    for (int c = 0; c < 3; c++) red[c][tid] = sum[c];
    __syncthreads();
    for (int s = 512; s > 0; s >>= 1) {
        if (tid < s)
            for (int c = 0; c < 3; c++) red[c][tid] += red[c][tid + s];
        __syncthreads();
    }
    if (tid == 0)
        for (int c = 0; c < 3; c++) { stats[c] = M[c]; stats[3 + c] = logf(red[c][0]); }
}

__global__ void k_final(const float* __restrict__ z2, const float* __restrict__ stats,
                        float* __restrict__ out, int n) {
    int i = blockIdx.x * blockDim.x + threadIdx.x;
    if (i < n) {
        int c = i % 3;
        out[i] = z2[i] - stats[c] - stats[3 + c];
    }
}

// ---- launch --------------------------------------------------------------

extern "C" void kernel_launch(void* const* d_in, const int* in_sizes, int n_in,
                              void* d_out, int out_size, void* d_ws, size_t ws_size,
                              hipStream_t stream) {
    const int*   edge_index = (const int*)d_in[0];
    const int*   src  = edge_index;
    const int*   dst  = edge_index + N_EDGES;
    const float* ew   = (const float*)d_in[1];
    const int*   home = (const int*)d_in[2];
    const int*   away = (const int*)d_in[3];
    const float* emb  = (const float*)d_in[4];
    const float* W0 = (const float*)d_in[5];  const float* b0 = (const float*)d_in[6];
    const float* W1 = (const float*)d_in[7];  const float* b1 = (const float*)d_in[8];
    const float* W2 = (const float*)d_in[9];  const float* b2 = (const float*)d_in[10];
    const float* l1W = (const float*)d_in[11]; const float* l1b = (const float*)d_in[12];
    const float* l3W = (const float*)d_in[13]; const float* l3b = (const float*)d_in[14];

    char* p = (char*)d_ws;
    float*          dinv      = (float*)p;          p += NPAD * 4;
    int*            cnt       = (int*)p;            p += NPAD * 4;
    int*            fill      = (int*)p;            p += NPAD * 4;
    int*            row_start = (int*)p;            p += (NPAD + 1024) * 4;
    int*            partial   = (int*)p;            p += 128 * 4;
    int2*           edges     = (int2*)p;           p += (size_t)N_EDGES * 8;
    unsigned short* xbA       = (unsigned short*)p; p += (size_t)N_TEAMS * 64 * 2;
    unsigned short* xbB       = (unsigned short*)p; p += (size_t)N_TEAMS * 64 * 2;
    float*          z2        = (float*)p;          p += (size_t)BATCH * 3 * 4;
    float*          stats     = (float*)p;

    const int scanBlocks = NPAD / 1024;  // 98

    // ---- CSR build (once, reused by all 3 layers) ----
    k_zero<<<NPAD / 256, 256, 0, stream>>>(cnt, NPAD);
    k_cnt<<<(N_EDGES + 255) / 256, 256, 0, stream>>>(dst, cnt, N_EDGES);
    k_scan1<<<scanBlocks, 1024, 0, stream>>>(cnt, row_start, partial, N_TEAMS);
    k_scan2<<<1, 128, 0, stream>>>(partial, scanBlocks);
    k_scan3<<<scanBlocks, 1024, 0, stream>>>(row_start, fill, partial);
    k_bucket<<<(N_EDGES + 255) / 256, 256, 0, stream>>>(src, dst, ew, fill, edges, N_EDGES);
    k_dinv<<<(N_TEAMS + 255) / 256, 256, 0, stream>>>(row_start, (const int*)edges, dinv, N_TEAMS);
    k_cvt<<<(N_TEAMS * 16 + 255) / 256, 256, 0, stream>>>(emb, dinv, xbA, N_TEAMS * 16);

    const int LBLOCKS = 2048;            // persistent: 8 blocks/CU by LDS
    const int LWAVES  = LBLOCKS * 4;     // 8192 waves, ~12 rows each

    // layer 0..2 fused: agg + GEMM + bias + leaky (+ dinv pre-scale for next)
    k_layer<<<LBLOCKS, 256, 0, stream>>>(xbA, row_start, (const long long*)edges, dinv,
                                         W0, b0, xbB, N_TEAMS, LWAVES, 1);
    k_layer<<<LBLOCKS, 256, 0, stream>>>(xbB, row_start, (const long long*)edges, dinv,
                                         W1, b1, xbA, N_TEAMS, LWAVES, 1);
    k_layer<<<LBLOCKS, 256, 0, stream>>>(xbA, row_start, (const long long*)edges, dinv,
                                         W2, b2, xbB, N_TEAMS, LWAVES, 0);

    // head + column log-softmax
    k_head<<<(BATCH + 255) / 256, 256, 0, stream>>>(xbB, home, away, l1W, l1b, l3W, l3b, z2, BATCH);
    k_stats<<<1, 1024, 0, stream>>>(z2, stats, BATCH);
    k_final<<<(BATCH * 3 + 255) / 256, 256, 0, stream>>>(z2, stats, (float*)d_out, BATCH * 3);
}

// Round 10
// 605.957 us; speedup vs baseline: 1.8514x; 1.1235x over previous
//
#include <hip/hip_runtime.h>
#include <math.h>

#define N_TEAMS 100000
#define N_EDGES 1600000
#define BATCH   16384
#define DIM     64
#define SLOPE   0.01f
#define NPAD    100352  // 98 * 1024

__device__ __forceinline__ float leaky(float v) { return v > 0.f ? v : SLOPE * v; }

__device__ __forceinline__ float bf2f(unsigned short u) {
    return __uint_as_float(((unsigned)u) << 16);
}
__device__ __forceinline__ unsigned short f2bf(float f) {
    unsigned b = __float_as_uint(f);
    unsigned r = b + 0x7FFFu + ((b >> 16) & 1u);  // RNE
    return (unsigned short)(r >> 16);
}
// packed edge: [31:17] = bf16 weight bits sans sign, [16:0] = src index
__device__ __forceinline__ float pw2f(unsigned p) {
    return __uint_as_float((p & 0xFFFE0000u) >> 1);
}

// ---- setup ---------------------------------------------------------------

__global__ void k_zero(int* __restrict__ cnt, int n) {
    int i = blockIdx.x * blockDim.x + threadIdx.x;
    if (i < n) cnt[i] = 0;
}

__global__ void k_cnt(const int* __restrict__ dst, int* __restrict__ cnt, int E) {
    int e = blockIdx.x * blockDim.x + threadIdx.x;
    if (e < E) atomicAdd(&cnt[__builtin_nontemporal_load(dst + e)], 1);
}

// ---- 2-level exclusive scan of cnt -> row_start (+ fill copy) ------------

__global__ __launch_bounds__(1024) void k_scan1(const int* __restrict__ cnt,
                                                int* __restrict__ excl,
                                                int* __restrict__ partial, int n) {
    __shared__ int s[1024];
    int tid = threadIdx.x;
    int i = blockIdx.x * 1024 + tid;
    int v = (i < n) ? cnt[i] : 0;
    s[tid] = v;
    __syncthreads();
    for (int off = 1; off < 1024; off <<= 1) {
        int t = (tid >= off) ? s[tid - off] : 0;
        __syncthreads();
        s[tid] += t;
        __syncthreads();
    }
    excl[i] = s[tid] - v;
    if (tid == 1023) partial[blockIdx.x] = s[1023];
}

__global__ __launch_bounds__(128) void k_scan2(int* __restrict__ partial, int nb) {
    __shared__ int s[128];
    int tid = threadIdx.x;
    int v = (tid < nb) ? partial[tid] : 0;
    s[tid] = v;
    __syncthreads();
    for (int off = 1; off < 128; off <<= 1) {
        int t = (tid >= off) ? s[tid - off] : 0;
        __syncthreads();
        s[tid] += t;
        __syncthreads();
    }
    if (tid < nb) partial[tid] = s[tid] - v;  // exclusive
}

__global__ __launch_bounds__(1024) void k_scan3(int* __restrict__ row_start,
                                                int* __restrict__ fill,
                                                const int* __restrict__ partial) {
    int i = blockIdx.x * 1024 + threadIdx.x;
    int v = row_start[i] + partial[blockIdx.x];
    row_start[i] = v;
    fill[i] = v;
}

// ---- bucket edges into CSR slots: packed u32 (w15 | src17) ---------------

__global__ void k_bucket(const int* __restrict__ src, const int* __restrict__ dst,
                         const float* __restrict__ w, int* __restrict__ fill,
                         unsigned* __restrict__ edges, int E) {
    int e = blockIdx.x * blockDim.x + threadIdx.x;
    if (e < E) {
        int s = __builtin_nontemporal_load(src + e);
        int d = __builtin_nontemporal_load(dst + e);
        float wv = __builtin_nontemporal_load(w + e);
        unsigned pk = (((unsigned)f2bf(wv) & 0x7FFFu) << 17) | (unsigned)s;
        int p = atomicAdd(&fill[d], 1);
        edges[p] = pk;
    }
}

// ---- dinv: thread per row, sum weights over own CSR range ----------------

__global__ void k_dinv(const int* __restrict__ row_start,
                       const unsigned* __restrict__ edges,
                       float* __restrict__ dinv, int n) {
    int r = blockIdx.x * blockDim.x + threadIdx.x;
    if (r >= n) return;
    int beg = row_start[r], end = row_start[r + 1];
    float s = 1.0f;  // self-loop
    for (int j = beg; j < end; j++) s += pw2f(edges[j]);
    dinv[r] = rsqrtf(fmaxf(s, 1e-12f));
}

// ---- emb -> pre-scaled bf16 table: xb[row][d] = dinv[row]*emb[row][d] ----

__global__ void k_cvt(const float* __restrict__ emb, const float* __restrict__ dinv,
                      unsigned short* __restrict__ xb, int n4) {
    int i = blockIdx.x * blockDim.x + threadIdx.x;
    if (i >= n4) return;
    int row = i >> 4;  // 16 float4 per row
    float di = dinv[row];
    float4 v = ((const float4*)emb)[i];
    ushort4 o;
    o.x = f2bf(di * v.x); o.y = f2bf(di * v.y);
    o.z = f2bf(di * v.z); o.w = f2bf(di * v.w);
    ((ushort4*)xb)[i] = o;
}

// ---- fused layer: y = leaky((A @ x) @ W + b) -----------------------------
// R4 structure: non-persistent, 4 rows/block (25000 blocks), one row/wave,
// 8-deep gather pipeline, W staged per block. Table pre-scaled by dinv;
// edges packed 4B (nt-loaded: stream-once, keep x-table in L2).

__global__ __launch_bounds__(256) void k_layer(
    const unsigned short* __restrict__ xb, const int* __restrict__ row_start,
    const unsigned* __restrict__ edges, const float* __restrict__ dinv,
    const float* __restrict__ W, const float* __restrict__ b,
    unsigned short* __restrict__ yb, int n, int scale_out) {
    __shared__ float Ws[64 * 64];
    int tid = threadIdx.x;
    const float4* Wv = (const float4*)W;
    float4* Wsv = (float4*)Ws;
#pragma unroll
    for (int i = 0; i < 4; i++) Wsv[tid + i * 256] = Wv[tid + i * 256];
    __syncthreads();
    int lane = tid & 63;
    int row = blockIdx.x * 4 + (tid >> 6);
    if (row >= n) return;
    int beg = row_start[row];
    int c = row_start[row + 1] - beg;
    float di = dinv[row];
    float acc = bf2f(xb[((unsigned)row << 6) + lane]);  // self (pre-scaled)
    const unsigned* ep = edges + beg;
    int j = 0;
    int chunks = c >> 3;
    if (chunks > 0) {
        unsigned ev[8];
#pragma unroll
        for (int k = 0; k < 8; k++) ev[k] = __builtin_nontemporal_load(ep + k);
        for (int t = 1; t <= chunks; t++) {
            float nv[8], xv[8];
#pragma unroll
            for (int k = 0; k < 8; k++) {
                int s = (int)(ev[k] & 0x1FFFFu);
                nv[k] = pw2f(ev[k]);
                xv[k] = bf2f(xb[((unsigned)s << 6) + lane]);  // 8 in-flight gathers
            }
            if (t < chunks) {
                const unsigned* np = ep + (size_t)t * 8;
#pragma unroll
                for (int k = 0; k < 8; k++) ev[k] = __builtin_nontemporal_load(np + k);
            }
#pragma unroll
            for (int k = 0; k < 8; k++) acc = fmaf(nv[k], xv[k], acc);
        }
        j = chunks * 8;
    }
    if (j + 4 <= c) {
        unsigned e0 = __builtin_nontemporal_load(ep + j + 0);
        unsigned e1 = __builtin_nontemporal_load(ep + j + 1);
        unsigned e2 = __builtin_nontemporal_load(ep + j + 2);
        unsigned e3 = __builtin_nontemporal_load(ep + j + 3);
        float x0 = bf2f(xb[((e0 & 0x1FFFFu) << 6) + lane]);
        float x1 = bf2f(xb[((e1 & 0x1FFFFu) << 6) + lane]);
        float x2 = bf2f(xb[((e2 & 0x1FFFFu) << 6) + lane]);
        float x3 = bf2f(xb[((e3 & 0x1FFFFu) << 6) + lane]);
        acc = fmaf(pw2f(e0), x0, acc);
        acc = fmaf(pw2f(e1), x1, acc);
        acc = fmaf(pw2f(e2), x2, acc);
        acc = fmaf(pw2f(e3), x3, acc);
        j += 4;
    }
    for (; j < c; j++) {
        unsigned e0 = __builtin_nontemporal_load(ep + j);
        acc = fmaf(pw2f(e0), bf2f(xb[((e0 & 0x1FFFFu) << 6) + lane]), acc);
    }
    acc *= di;
    // in-wave GEMM: o[lane] = sum_k acc[k] * W[k][lane]
    float o = b[lane];
#pragma unroll
    for (int k = 0; k < 64; k++) {
        float xk = __shfl(acc, k, 64);
        o = fmaf(xk, Ws[k * 64 + lane], o);
    }
    o = leaky(o);
    if (scale_out) o *= di;
    yb[((unsigned)row << 6) + lane] = f2bf(o);
}

// ---- head MLP (bf16 activations in, row-major) ---------------------------

__global__ __launch_bounds__(256) void k_head(
    const unsigned short* __restrict__ xb, const int* __restrict__ home,
    const int* __restrict__ away, const float* __restrict__ W1,
    const float* __restrict__ b1, const float* __restrict__ W3,
    const float* __restrict__ b3, float* __restrict__ z2, int B) {
    __shared__ float W1s[128 * 6];
    __shared__ float b1s[6], W3s[18], b3s[3];
    int tid = threadIdx.x;
    for (int i = tid; i < 768; i += 256) W1s[i] = W1[i];
    if (tid < 6) b1s[tid] = b1[tid];
    if (tid < 18) W3s[tid] = W3[tid];
    if (tid < 3) b3s[tid] = b3[tid];
    __syncthreads();
    int i = blockIdx.x * 256 + tid;
    if (i >= B) return;
    float z1[6];
#pragma unroll
    for (int j = 0; j < 6; j++) z1[j] = b1s[j];
    const uint4* rows[2];
    rows[0] = (const uint4*)(xb + (size_t)home[i] * 64);
    rows[1] = (const uint4*)(xb + (size_t)away[i] * 64);
#pragma unroll
    for (int h = 0; h < 2; h++) {
        const uint4* r = rows[h];
        int base = h * 64;
#pragma unroll
        for (int k = 0; k < 8; k++) {   // 8 x uint4 = 64 bf16 dims
            uint4 v = r[k];
            unsigned uu[4] = {v.x, v.y, v.z, v.w};
#pragma unroll
            for (int t = 0; t < 4; t++) {
                float fx = bf2f((unsigned short)(uu[t] & 0xFFFF));
                float fy = bf2f((unsigned short)(uu[t] >> 16));
                int d = base + k * 8 + t * 2;
#pragma unroll
                for (int j = 0; j < 6; j++) {
                    z1[j] = fmaf(fx, W1s[d * 6 + j], z1[j]);
                    z1[j] = fmaf(fy, W1s[(d + 1) * 6 + j], z1[j]);
                }
            }
        }
    }
#pragma unroll
    for (int j = 0; j < 6; j++) z1[j] = leaky(z1[j]);
#pragma unroll
    for (int c = 0; c < 3; c++) {
        float s = b3s[c];
#pragma unroll
        for (int j = 0; j < 6; j++) s = fmaf(z1[j], W3s[j * 3 + c], s);
        z2[(size_t)i * 3 + c] = leaky(s);
    }
}

// ---- column-wise log-softmax ---------------------------------------------

__global__ __launch_bounds__(1024) void k_stats(const float* __restrict__ z2,
                                                float* __restrict__ stats, int B) {
    __shared__ float red[3][1024];
    int tid = threadIdx.x;
    float m[3] = {-1e30f, -1e30f, -1e30f};
    for (int i = tid; i < B; i += 1024) {
        m[0] = fmaxf(m[0], z2[3 * i + 0]);
        m[1] = fmaxf(m[1], z2[3 * i + 1]);
        m[2] = fmaxf(m[2], z2[3 * i + 2]);
    }
    for (int c = 0; c < 3; c++) red[c][tid] = m[c];
    __syncthreads();
    for (int s = 512; s > 0; s >>= 1) {
        if (tid < s)
            for (int c = 0; c < 3; c++) red[c][tid] = fmaxf(red[c][tid], red[c][tid + s]);
        __syncthreads();
    }
    float M[3];
    for (int c = 0; c < 3; c++) M[c] = red[c][0];
    __syncthreads();
    float sum[3] = {0.f, 0.f, 0.f};
    for (int i = tid; i < B; i += 1024) {
        sum[0] += expf(z2[3 * i + 0] - M[0]);
        sum[1] += expf(z2[3 * i + 1] - M[1]);
        sum[2] += expf(z2[3 * i + 2] - M[2]);
    }
    for (int c = 0; c < 3; c++) red[c][tid] = sum[c];
    __syncthreads();
    for (int s = 512; s > 0; s >>= 1) {
        if (tid < s)
            for (int c = 0; c < 3; c++) red[c][tid] += red[c][tid + s];
        __syncthreads();
    }
    if (tid == 0)
        for (int c = 0; c < 3; c++) { stats[c] = M[c]; stats[3 + c] = logf(red[c][0]); }
}

__global__ void k_final(const float* __restrict__ z2, const float* __restrict__ stats,
                        float* __restrict__ out, int n) {
    int i = blockIdx.x * blockDim.x + threadIdx.x;
    if (i < n) {
        int c = i % 3;
        out[i] = z2[i] - stats[c] - stats[3 + c];
    }
}

// ---- launch --------------------------------------------------------------

extern "C" void kernel_launch(void* const* d_in, const int* in_sizes, int n_in,
                              void* d_out, int out_size, void* d_ws, size_t ws_size,
                              hipStream_t stream) {
    const int*   edge_index = (const int*)d_in[0];
    const int*   src  = edge_index;
    const int*   dst  = edge_index + N_EDGES;
    const float* ew   = (const float*)d_in[1];
    const int*   home = (const int*)d_in[2];
    const int*   away = (const int*)d_in[3];
    const float* emb  = (const float*)d_in[4];
    const float* W0 = (const float*)d_in[5];  const float* b0 = (const float*)d_in[6];
    const float* W1 = (const float*)d_in[7];  const float* b1 = (const float*)d_in[8];
    const float* W2 = (const float*)d_in[9];  const float* b2 = (const float*)d_in[10];
    const float* l1W = (const float*)d_in[11]; const float* l1b = (const float*)d_in[12];
    const float* l3W = (const float*)d_in[13]; const float* l3b = (const float*)d_in[14];

    char* p = (char*)d_ws;
    float*          dinv      = (float*)p;          p += NPAD * 4;
    int*            cnt       = (int*)p;            p += NPAD * 4;
    int*            fill      = (int*)p;            p += NPAD * 4;
    int*            row_start = (int*)p;            p += (NPAD + 1024) * 4;
    int*            partial   = (int*)p;            p += 128 * 4;
    unsigned*       edges     = (unsigned*)p;       p += (size_t)N_EDGES * 4;
    unsigned short* xbA       = (unsigned short*)p; p += (size_t)N_TEAMS * 64 * 2;
    unsigned short* xbB       = (unsigned short*)p; p += (size_t)N_TEAMS * 64 * 2;
    float*          z2        = (float*)p;          p += (size_t)BATCH * 3 * 4;
    float*          stats     = (float*)p;

    const int scanBlocks = NPAD / 1024;  // 98

    // ---- CSR build (once, reused by all 3 layers) ----
    k_zero<<<NPAD / 256, 256, 0, stream>>>(cnt, NPAD);
    k_cnt<<<(N_EDGES + 255) / 256, 256, 0, stream>>>(dst, cnt, N_EDGES);
    k_scan1<<<scanBlocks, 1024, 0, stream>>>(cnt, row_start, partial, N_TEAMS);
    k_scan2<<<1, 128, 0, stream>>>(partial, scanBlocks);
    k_scan3<<<scanBlocks, 1024, 0, stream>>>(row_start, fill, partial);
    k_bucket<<<(N_EDGES + 255) / 256, 256, 0, stream>>>(src, dst, ew, fill, edges, N_EDGES);
    k_dinv<<<(N_TEAMS + 255) / 256, 256, 0, stream>>>(row_start, edges, dinv, N_TEAMS);
    k_cvt<<<(N_TEAMS * 16 + 255) / 256, 256, 0, stream>>>(emb, dinv, xbA, N_TEAMS * 16);

    const int LBLOCKS = (N_TEAMS + 3) / 4;  // 25000, non-persistent (R4 codegen)

    // layer 0..2 fused: agg + GEMM + bias + leaky (+ dinv pre-scale for next)
    k_layer<<<LBLOCKS, 256, 0, stream>>>(xbA, row_start, edges, dinv, W0, b0, xbB, N_TEAMS, 1);
    k_layer<<<LBLOCKS, 256, 0, stream>>>(xbB, row_start, edges, dinv, W1, b1, xbA, N_TEAMS, 1);
    k_layer<<<LBLOCKS, 256, 0, stream>>>(xbA, row_start, edges, dinv, W2, b2, xbB, N_TEAMS, 0);

    // head + column log-softmax
    k_head<<<(BATCH + 255) / 256, 256, 0, stream>>>(xbB, home, away, l1W, l1b, l3W, l3b, z2, BATCH);
    k_stats<<<1, 1024, 0, stream>>>(z2, stats, BATCH);
    k_final<<<(BATCH * 3 + 255) / 256, 256, 0, stream>>>(z2, stats, (float*)d_out, BATCH * 3);
}